// Round 18
// baseline (2993.559 us; speedup 1.0000x reference)
//
#include <hip/hip_runtime.h>

#define V_N 20000
#define E_N 100000
#define NODE_IN_F 128
#define EDGE_IN_F 128
#define H 64
#define EDGE_HID 128
#define OUT_F 64
#define STEPS 9

#define NB 16       // nodes per k_msg2 block (o-split into 4 chunks of 16)
#define PSTR 136    // P k-stride in shorts (128 + 8 pad) -> row 272 B, 16B-aligned

typedef __attribute__((ext_vector_type(8))) short bf16x8;
typedef __attribute__((ext_vector_type(4))) float f32x4;

__device__ __forceinline__ unsigned short f2bf(float f) {
    union { float f; unsigned int u; } v; v.f = f;
    unsigned int u = v.u;
    unsigned int r = (u + 0x7fffu + ((u >> 16) & 1u)) >> 16;  // RNE
    return (unsigned short)r;
}

__device__ __forceinline__ float dot4(float4 w, float4 x) {
    return w.x * x.x + w.y * x.y + w.z * x.z + w.w * x.w;
}

// h0 = relu(nf@w1.T+b1)@w2.T+b2 (V,64) fp32; zero agg; hb = h0-row @ b_e2-matrix
__global__ __launch_bounds__(64) void k_project(
    const float* __restrict__ nf,
    const float* __restrict__ w1, const float* __restrict__ b1,
    const float* __restrict__ w2, const float* __restrict__ b2,
    const float* __restrict__ b2e,
    float* __restrict__ h, float* __restrict__ agg, float* __restrict__ hb)
{
    int v = blockIdx.x, t = threadIdx.x;
    __shared__ float x[NODE_IN_F], tm[H];
    const float* row = nf + (size_t)v * NODE_IN_F;
    x[t] = row[t];
    x[t + 64] = row[t + 64];
    agg[(size_t)v * H + t] = 0.f;
    __syncthreads();
    float acc = b1[t];
    const float4* wr = (const float4*)(w1 + (size_t)t * NODE_IN_F);
    #pragma unroll
    for (int q = 0; q < NODE_IN_F / 4; ++q) acc += dot4(wr[q], *(const float4*)&x[q * 4]);
    tm[t] = fmaxf(acc, 0.f);
    __syncthreads();
    float acc2 = b2[t];
    const float4* wr2 = (const float4*)(w2 + (size_t)t * H);
    #pragma unroll
    for (int q = 0; q < H / 4; ++q) acc2 += dot4(wr2[q], *(const float4*)&tm[q * 4]);
    h[(size_t)v * H + t] = acc2;
    __syncthreads();
    x[t] = acc2;           // reuse x as h-row
    __syncthreads();
    float acc3 = 0.f;
    for (int i = 0; i < H; ++i) acc3 += x[i] * b2e[i * 64 + t];
    hb[(size_t)v * H + t] = acc3;
}

// ---------------- CSR build (src/dst static; rebuilt each launch) ----------------
__global__ void k_zero_cnt(int* __restrict__ cnt) {
    int i = blockIdx.x * 256 + threadIdx.x;
    if (i < V_N) cnt[i] = 0;
}
__global__ void k_csr_count(const int* __restrict__ src, int* __restrict__ cnt) {
    int e = blockIdx.x * 256 + threadIdx.x;
    if (e < E_N) atomicAdd(&cnt[src[e]], 1);
}
// single-block exclusive scan of cnt -> offs (V+1), cursor copy
__global__ __launch_bounds__(256) void k_csr_scan(
    const int* __restrict__ cnt, int* __restrict__ offs, int* __restrict__ cursor)
{
    __shared__ int part[256];
    int t = threadIdx.x;
    const int CH = 79;                  // 256*79 = 20224 >= V_N
    int s = 0;
    for (int i = 0; i < CH; ++i) {
        int idx = t * CH + i;
        if (idx < V_N) s += cnt[idx];
    }
    part[t] = s;
    __syncthreads();
    if (t == 0) {
        int run = 0;
        for (int i = 0; i < 256; ++i) { int v = part[i]; part[i] = run; run += v; }
    }
    __syncthreads();
    int run = part[t];
    for (int i = 0; i < CH; ++i) {
        int idx = t * CH + i;
        if (idx < V_N) { offs[idx] = run; cursor[idx] = run; run += cnt[idx]; }
    }
    if (t == 255) offs[V_N] = run;      // == E_N
}
__global__ void k_csr_scatter(
    const int* __restrict__ src, const int* __restrict__ dst,
    int* __restrict__ cursor, int* __restrict__ sortpos, int* __restrict__ dst_s)
{
    int e = blockIdx.x * 256 + threadIdx.x;
    if (e < E_N) {
        int p = atomicAdd(&cursor[src[e]], 1);
        sortpos[e] = p;
        dst_s[p] = dst[e];
    }
}

// g_s[sortpos[e]] = relu(ef[e] @ w_e1.T + b_e1) -> (E,128) bf16, src-sorted rows.
__global__ __launch_bounds__(256) void k_edge_g(
    const float* __restrict__ ef,
    const float* __restrict__ w1, const float* __restrict__ b1,
    const int* __restrict__ sortpos,
    unsigned short* __restrict__ g)
{
    int tid = threadIdx.x;
    int e0 = blockIdx.x * 32;
    int c = tid & 127, eg = tid >> 7;
    __shared__ float xe[32][132];
    __shared__ int sp_s[32];
    if (tid < 32) sp_s[tid] = sortpos[e0 + tid];
    for (int idx = tid; idx < 1024; idx += 256) {
        int e = idx >> 5, kq = idx & 31;
        float4 v = *(const float4*)(ef + (size_t)(e0 + e) * EDGE_IN_F + kq * 4);
        *(float4*)&xe[e][kq * 4] = v;
    }
    __syncthreads();
    float acc[16];
    #pragma unroll
    for (int j = 0; j < 16; ++j) acc[j] = b1[c];
    const float4* wr = (const float4*)(w1 + (size_t)c * EDGE_IN_F);
    for (int kb = 0; kb < EDGE_IN_F / 4; ++kb) {
        float4 w = wr[kb];
        #pragma unroll
        for (int j = 0; j < 16; ++j) {
            float4 x = *(const float4*)&xe[eg * 16 + j][kb * 4];
            acc[j] += dot4(w, x);
        }
    }
    #pragma unroll
    for (int j = 0; j < 16; ++j)
        g[(size_t)sp_s[eg * 16 + j] * EDGE_HID + c] = f2bf(fmaxf(acc[j], 0.f));
}

// w2rt2 layout: row r2 = c*2048 + k*16 + u  (c = o-chunk, u = o within chunk)
// holds w_e2[(i*64 + (c*16+u)) * 128 + k] over i in [0,64), bf16. 1 MB one-time.
__global__ __launch_bounds__(64) void k_w2rt(
    const float* __restrict__ w2, unsigned short* __restrict__ w2rt)
{
    int r2 = blockIdx.x, i = threadIdx.x;
    int c = r2 >> 11, k = (r2 >> 4) & 127, u = r2 & 15;
    int o = c * 16 + u;
    float v = w2[(size_t)(i * 64 + o) * EDGE_HID + k];
    w2rt[(size_t)r2 * 64 + i] = f2bf(v);
}

// Fused per-node message kernel v4. Block = 16 nodes, 512 threads (8 waves),
// LDS 69,632 B -> 2 blocks/CU -> 4 waves/SIMD. Rationale: R13/R15/R16 proved
// 1024-thread blocks are pinned at a 64-VGPR budget (both launch_bounds
// variants ignored) -> permanent scratch spills. R7 proved the 512-thread
// shape compiles to 124 VGPR spill-free. NB=16 halves LDS so TWO such blocks
// co-reside, reaching the same 16 waves/CU the 1024 config had, without the
// spills. Phase A is also leaner: M=16 = exactly one dense n-tile (half the
// MFMAs/regs of NB=32). Cost: w2rt L2 stream 625 MB -> 1.22 GB/dispatch
// (still ~3.5% of L2 BW ceiling).
// o in 4 chunks of 16: phase A: P[n][o_w][k] = sum_i h[v0+n][i]*W2[(i,o)][k];
// wave wv owns k-pairs [wv*8, wv*8+8) (MFMA 16x16x32, depth-2 pipelined B
// loads, packed (k,k+1) u32 ds_writes); barrier; phase B: wave wv owns nodes
// wv*2..+2: msg[e, c*16+m] = sum_k g_s[e,k]*P[n][m][k] via 4 chained MFMAs
// per 16-edge group + hb bias + atomicAdd scatter to agg[dst].
__global__ __launch_bounds__(512) void k_msg2(
    const float* __restrict__ h,
    const unsigned short* __restrict__ g_s,
    const unsigned short* __restrict__ w2rt,
    const float* __restrict__ hb,
    const int* __restrict__ offs,
    const int* __restrict__ dst_s,
    float* __restrict__ agg)
{
    int tid = threadIdx.x;
    int wv = tid >> 6, lane = tid & 63;
    int m = lane & 15, q = lane >> 4;
    int v0 = blockIdx.x * NB;
    __shared__ unsigned short P[256 * PSTR];   // 69,632 B -> 2 blocks/CU
    unsigned short* Pl = P;

    // ---- prefetch phase-B edge data: 2 nodes per wave, held across all chunks
    int esA[2], dA[2];
    bf16x8 gA0[2], gA1[2], gA2[2], gA3[2];
    #pragma unroll
    for (int nn = 0; nn < 2; ++nn) {
        int vv = v0 + wv * 2 + nn;
        int es_ = offs[vv], ee_ = offs[vv + 1];
        esA[nn] = es_; dA[nn] = ee_ - es_;
        int j = es_ + m;
        if (j >= ee_) j = (ee_ > 0) ? ee_ - 1 : 0;
        const unsigned short* ga = g_s + (size_t)j * EDGE_HID + q * 8;
        gA0[nn] = *(const bf16x8*)(ga);
        gA1[nn] = *(const bf16x8*)(ga + 32);
        gA2[nn] = *(const bf16x8*)(ga + 64);
        gA3[nn] = *(const bf16x8*)(ga + 96);
    }

    // ---- phase-A A-fragments: h rows for 16 nodes (1 dense n-tile), fp32 -> bf16
    bf16x8 Ah0, Ah1;
#define PACK8(DST, XA, XB) { \
    DST[0] = (short)f2bf(XA.x); DST[1] = (short)f2bf(XA.y); \
    DST[2] = (short)f2bf(XA.z); DST[3] = (short)f2bf(XA.w); \
    DST[4] = (short)f2bf(XB.x); DST[5] = (short)f2bf(XB.y); \
    DST[6] = (short)f2bf(XB.z); DST[7] = (short)f2bf(XB.w); }
    {
        const float* hr0 = h + (size_t)(v0 + m) * H;
        float4 x0 = *(const float4*)(hr0 + q * 8);
        float4 x1 = *(const float4*)(hr0 + q * 8 + 4);
        float4 x2 = *(const float4*)(hr0 + 32 + q * 8);
        float4 x3 = *(const float4*)(hr0 + 32 + q * 8 + 4);
        PACK8(Ah0, x0, x1)
        PACK8(Ah1, x2, x3)
    }
#undef PACK8

// B-frag load for k-pair p (within chunk): (k0,i-half0),(k0,i-half1),(k1,i0),(k1,i1)
#define LB2(Bn, p_) { \
    const unsigned short* b_ = wb + (size_t)(p_) * 2048; \
    Bn##0 = *(const bf16x8*)(b_); \
    Bn##1 = *(const bf16x8*)(b_ + 32); \
    Bn##2 = *(const bf16x8*)(b_ + 1024); \
    Bn##3 = *(const bf16x8*)(b_ + 1056); }

// compute k-pair p: 4 dense MFMAs (2 k x 2 i-halves x 1 n-tile), pack (k,k+1)
// -> u32, 4 ds_write_b32. D: row = node (q*4+r), col = o_w (m).
#define CP2(p_, Bn) { \
    f32x4 d00 = {0.f,0.f,0.f,0.f}, d10 = {0.f,0.f,0.f,0.f}; \
    d00 = __builtin_amdgcn_mfma_f32_16x16x32_bf16(Ah0, Bn##0, d00, 0, 0, 0); \
    d00 = __builtin_amdgcn_mfma_f32_16x16x32_bf16(Ah1, Bn##1, d00, 0, 0, 0); \
    d10 = __builtin_amdgcn_mfma_f32_16x16x32_bf16(Ah0, Bn##2, d10, 0, 0, 0); \
    d10 = __builtin_amdgcn_mfma_f32_16x16x32_bf16(Ah1, Bn##3, d10, 0, 0, 0); \
    unsigned short* pw_ = Pl + (size_t)((q * 4) * 16 + m) * PSTR + (p_) * 2; \
    unsigned int pk_; \
    pk_ = (unsigned)f2bf(d00[0]) | ((unsigned)f2bf(d10[0]) << 16); *(unsigned int*)(pw_ +    0) = pk_; \
    pk_ = (unsigned)f2bf(d00[1]) | ((unsigned)f2bf(d10[1]) << 16); *(unsigned int*)(pw_ + 2176) = pk_; \
    pk_ = (unsigned)f2bf(d00[2]) | ((unsigned)f2bf(d10[2]) << 16); *(unsigned int*)(pw_ + 4352) = pk_; \
    pk_ = (unsigned)f2bf(d00[3]) | ((unsigned)f2bf(d10[3]) << 16); *(unsigned int*)(pw_ + 6528) = pk_; }

    for (int c = 0; c < 4; ++c) {
        __syncthreads();               // P safe to overwrite (phase B of c-1 done)
        // ---- phase A for chunk c: wave wv owns k-pairs [wv*8, wv*8+8)
        const unsigned short* wb = w2rt + (size_t)c * 131072 + m * 64 + q * 8;
        int pg = wv * 8;
        bf16x8 Bu0, Bu1, Bu2, Bu3, Bv0, Bv1, Bv2, Bv3;
        LB2(Bu, pg + 0)
        LB2(Bv, pg + 1)
        CP2(pg + 0, Bu) LB2(Bu, pg + 2)
        CP2(pg + 1, Bv) LB2(Bv, pg + 3)
        CP2(pg + 2, Bu) LB2(Bu, pg + 4)
        CP2(pg + 3, Bv) LB2(Bv, pg + 5)
        CP2(pg + 4, Bu) LB2(Bu, pg + 6)
        CP2(pg + 5, Bv) LB2(Bv, pg + 7)
        CP2(pg + 6, Bu)
        CP2(pg + 7, Bv)
        __syncthreads();
        // ---- phase B for chunk c: wave wv owns nodes wv*2, wv*2+1
        #pragma unroll
        for (int nn = 0; nn < 2; ++nn) {
            int d_ = dA[nn];
            if (d_ <= 0) continue;
            int n = wv * 2 + nn;
            int vv = v0 + n;
            float hbv = hb[(size_t)vv * H + c * 16 + m];
            const unsigned short* pr = Pl + (size_t)(n * 16 + m) * PSTR + q * 8;
            bf16x8 Bf0 = *(const bf16x8*)(pr);
            bf16x8 Bf1 = *(const bf16x8*)(pr + 32);
            bf16x8 Bf2 = *(const bf16x8*)(pr + 64);
            bf16x8 Bf3 = *(const bf16x8*)(pr + 96);
            bf16x8 a0 = gA0[nn], a1 = gA1[nn], a2 = gA2[nn], a3 = gA3[nn];
            int es_ = esA[nn];
            for (int t = 0; t < d_; t += 16) {
                if (t > 0) {
                    int j = es_ + t + m;
                    if (j >= es_ + d_) j = es_ + d_ - 1;
                    const unsigned short* ga = g_s + (size_t)j * EDGE_HID + q * 8;
                    a0 = *(const bf16x8*)(ga);
                    a1 = *(const bf16x8*)(ga + 32);
                    a2 = *(const bf16x8*)(ga + 64);
                    a3 = *(const bf16x8*)(ga + 96);
                }
                f32x4 dd = {0.f, 0.f, 0.f, 0.f};
                dd = __builtin_amdgcn_mfma_f32_16x16x32_bf16(a0, Bf0, dd, 0, 0, 0);
                dd = __builtin_amdgcn_mfma_f32_16x16x32_bf16(a1, Bf1, dd, 0, 0, 0);
                dd = __builtin_amdgcn_mfma_f32_16x16x32_bf16(a2, Bf2, dd, 0, 0, 0);
                dd = __builtin_amdgcn_mfma_f32_16x16x32_bf16(a3, Bf3, dd, 0, 0, 0);
                #pragma unroll
                for (int r = 0; r < 4; ++r) {
                    int erow = q * 4 + r;
                    if (t + erow < d_) {
                        atomicAdd(&agg[(size_t)dst_s[es_ + t + erow] * H + c * 16 + m],
                                  dd[r] + hbv);
                    }
                }
            }
        }
    }
#undef LB2
#undef CP2
}

// GRU over 16 nodes/block; x=relu(agg+b_conv); agg re-zeroed; epilogue: hb = newh @ b_e2
__global__ __launch_bounds__(256) void k_gru(
    float* __restrict__ agg, const float* __restrict__ b_conv,
    const float* __restrict__ w_ih, const float* __restrict__ w_hh,
    const float* __restrict__ b_ih, const float* __restrict__ b_hh,
    const float* __restrict__ b2e,
    float* __restrict__ h, float* __restrict__ hb)
{
    int tid = threadIdx.x;
    int o = tid & 63, grp = tid >> 6;
    int vbase = blockIdx.x * 16;
    __shared__ float xl[16][68], hl[16][68];
    for (int idx = tid; idx < 16 * 64; idx += 256) {
        int n = idx >> 6, i = idx & 63;
        size_t p = (size_t)(vbase + n) * H + i;
        float a = agg[p];
        agg[p] = 0.f;
        xl[n][i] = fmaxf(a + b_conv[i], 0.f);
        hl[n][i] = h[p];
    }
    __syncthreads();
    float gir[4], giz[4], gin[4], ghr[4], ghz[4], ghn[4];
    #pragma unroll
    for (int n = 0; n < 4; ++n) {
        gir[n] = b_ih[o];       ghr[n] = b_hh[o];
        giz[n] = b_ih[64 + o];  ghz[n] = b_hh[64 + o];
        gin[n] = b_ih[128 + o]; ghn[n] = b_hh[128 + o];
    }
    const float4* wir = (const float4*)(w_ih + (size_t)o * H);
    const float4* wiz = (const float4*)(w_ih + (size_t)(64 + o) * H);
    const float4* win = (const float4*)(w_ih + (size_t)(128 + o) * H);
    const float4* whr = (const float4*)(w_hh + (size_t)o * H);
    const float4* whz = (const float4*)(w_hh + (size_t)(64 + o) * H);
    const float4* whn = (const float4*)(w_hh + (size_t)(128 + o) * H);
    #pragma unroll 4
    for (int qq = 0; qq < H / 4; ++qq) {
        float4 a1 = wir[qq], a2 = wiz[qq], a3 = win[qq];
        float4 c1 = whr[qq], c2 = whz[qq], c3 = whn[qq];
        #pragma unroll
        for (int n = 0; n < 4; ++n) {
            float4 xv = *(const float4*)&xl[grp * 4 + n][qq * 4];
            float4 hv = *(const float4*)&hl[grp * 4 + n][qq * 4];
            gir[n] += dot4(a1, xv); giz[n] += dot4(a2, xv); gin[n] += dot4(a3, xv);
            ghr[n] += dot4(c1, hv); ghz[n] += dot4(c2, hv); ghn[n] += dot4(c3, hv);
        }
    }
    float newh[4];
    #pragma unroll
    for (int n = 0; n < 4; ++n) {
        float hv = hl[grp * 4 + n][o];
        float r = 1.f / (1.f + __expf(-(gir[n] + ghr[n])));
        float z = 1.f / (1.f + __expf(-(giz[n] + ghz[n])));
        float na = gin[n] + r * ghn[n];
        float tn = 1.f - 2.f / (__expf(2.f * na) + 1.f);   // tanh
        newh[n] = (1.f - z) * tn + z * hv;
        h[(size_t)(vbase + grp * 4 + n) * H + o] = newh[n];
    }
    __syncthreads();                 // xl dead; reuse for new h
    #pragma unroll
    for (int n = 0; n < 4; ++n) xl[grp * 4 + n][o] = newh[n];
    __syncthreads();
    float hbacc[4] = {0.f, 0.f, 0.f, 0.f};
    for (int i = 0; i < H; ++i) {
        float w = b2e[i * 64 + o];
        #pragma unroll
        for (int n = 0; n < 4; ++n) hbacc[n] += xl[grp * 4 + n][i] * w;
    }
    #pragma unroll
    for (int n = 0; n < 4; ++n)
        hb[(size_t)(vbase + grp * 4 + n) * H + o] = hbacc[n];
}

// out = relu(h @ w_d1.T + b_d1) @ w_d2.T + b_d2  -> fp32
__global__ __launch_bounds__(64) void k_decoder(
    const float* __restrict__ h,
    const float* __restrict__ w1, const float* __restrict__ b1,
    const float* __restrict__ w2, const float* __restrict__ b2,
    float* __restrict__ out)
{
    int v = blockIdx.x, t = threadIdx.x;
    __shared__ float hl[H], tl[H];
    hl[t] = h[(size_t)v * H + t];
    __syncthreads();
    float acc = b1[t];
    const float4* wr = (const float4*)(w1 + (size_t)t * H);
    #pragma unroll
    for (int q = 0; q < H / 4; ++q) acc += dot4(wr[q], *(const float4*)&hl[q * 4]);
    tl[t] = fmaxf(acc, 0.f);
    __syncthreads();
    float acc2 = b2[t];
    const float4* wr2 = (const float4*)(w2 + (size_t)t * H);
    #pragma unroll
    for (int q = 0; q < H / 4; ++q) acc2 += dot4(wr2[q], *(const float4*)&tl[q * 4]);
    out[(size_t)v * OUT_F + t] = acc2;
}

extern "C" void kernel_launch(void* const* d_in, const int* in_sizes, int n_in,
                              void* d_out, int out_size, void* d_ws, size_t ws_size,
                              hipStream_t stream) {
    const float* nf     = (const float*)d_in[0];
    const float* ef     = (const float*)d_in[1];
    const int* src      = (const int*)d_in[2];
    const int* dst      = (const int*)d_in[3];
    const float* w_p1   = (const float*)d_in[4];
    const float* b_p1   = (const float*)d_in[5];
    const float* w_p2   = (const float*)d_in[6];
    const float* b_p2   = (const float*)d_in[7];
    const float* w_e1   = (const float*)d_in[8];
    const float* b_e1   = (const float*)d_in[9];
    const float* w_e2   = (const float*)d_in[10];
    const float* b_e2   = (const float*)d_in[11];
    const float* b_conv = (const float*)d_in[12];
    const float* w_ih   = (const float*)d_in[13];
    const float* w_hh   = (const float*)d_in[14];
    const float* b_ih   = (const float*)d_in[15];
    const float* b_hh   = (const float*)d_in[16];
    const float* w_d1   = (const float*)d_in[17];
    const float* b_d1   = (const float*)d_in[18];
    const float* w_d2   = (const float*)d_in[19];
    const float* b_d2   = (const float*)d_in[20];

    // d_ws layout (total 42,008,576 B):
    //   g_s     : E*128 bf16 (src-sorted rows)      @ 0          25,600,000
    //   w2rt2   : 8192*64 bf16 (chunked reindex)    @ 25,600,000  1,048,576
    //   h       : V*64 f32                          @ 26,648,576  5,120,000
    //   agg     : V*64 f32                          @ 31,768,576  5,120,000
    //   hb      : V*64 f32                          @ 36,888,576  5,120,000
    char* ws = (char*)d_ws;
    unsigned short* g_s  = (unsigned short*)(ws);
    unsigned short* w2rt = (unsigned short*)(ws + 25600000LL);
    float* h             = (float*)(ws + 26648576LL);
    float* agg           = (float*)(ws + 31768576LL);
    float* hb            = (float*)(ws + 36888576LL);

    // CSR scratch lives in d_out (5,120,000 B; fully overwritten by k_decoder
    // at the end, so it is legal intra-launch scratch). Total used: 1,040,016 B.
    char* ob = (char*)d_out;
    int* offs            = (int*)(ob);               //   80,016 B ((V+1) i32, padded)
    int* cursor          = (int*)(ob +   80016LL);   //   80,000 B
    int* cnt             = (int*)(ob +  160016LL);   //   80,000 B
    int* sortpos         = (int*)(ob +  240016LL);   //  400,000 B
    int* dst_s           = (int*)(ob +  640016LL);   //  400,000 B

    k_project<<<V_N, 64, 0, stream>>>(nf, w_p1, b_p1, w_p2, b_p2, b_e2, h, agg, hb);
    k_zero_cnt<<<(V_N + 255) / 256, 256, 0, stream>>>(cnt);
    k_csr_count<<<(E_N + 255) / 256, 256, 0, stream>>>(src, cnt);
    k_csr_scan<<<1, 256, 0, stream>>>(cnt, offs, cursor);
    k_csr_scatter<<<(E_N + 255) / 256, 256, 0, stream>>>(src, dst, cursor, sortpos, dst_s);
    k_edge_g<<<E_N / 32, 256, 0, stream>>>(ef, w_e1, b_e1, sortpos, g_s);
    k_w2rt<<<8192, 64, 0, stream>>>(w_e2, w2rt);
    for (int s = 0; s < STEPS; ++s) {
        k_msg2<<<V_N / NB, 512, 0, stream>>>(h, g_s, w2rt, hb, offs, dst_s, agg);
        k_gru<<<V_N / 16, 256, 0, stream>>>(agg, b_conv, w_ih, w_hh, b_ih, b_hh, b_e2, h, hb);
    }
    k_decoder<<<V_N, 64, 0, stream>>>(h, w_d1, b_d1, w_d2, b_d2, (float*)d_out);
}

// Round 19
// 2981.371 us; speedup vs baseline: 1.0041x; 1.0041x over previous
//
#include <hip/hip_runtime.h>

#define V_N 20000
#define E_N 100000
#define NODE_IN_F 128
#define EDGE_IN_F 128
#define H 64
#define EDGE_HID 128
#define OUT_F 64
#define STEPS 9

#define NB 16       // nodes per k_msg2 block (o-split into 4 chunks of 16)

typedef __attribute__((ext_vector_type(8))) short bf16x8;
typedef __attribute__((ext_vector_type(4))) float f32x4;

__device__ __forceinline__ unsigned short f2bf(float f) {
    union { float f; unsigned int u; } v; v.f = f;
    unsigned int u = v.u;
    unsigned int r = (u + 0x7fffu + ((u >> 16) & 1u)) >> 16;  // RNE
    return (unsigned short)r;
}

__device__ __forceinline__ float dot4(float4 w, float4 x) {
    return w.x * x.x + w.y * x.y + w.z * x.z + w.w * x.w;
}

// h0 = relu(nf@w1.T+b1)@w2.T+b2 (V,64) fp32; zero agg; hb = h0-row @ b_e2-matrix
__global__ __launch_bounds__(64) void k_project(
    const float* __restrict__ nf,
    const float* __restrict__ w1, const float* __restrict__ b1,
    const float* __restrict__ w2, const float* __restrict__ b2,
    const float* __restrict__ b2e,
    float* __restrict__ h, float* __restrict__ agg, float* __restrict__ hb)
{
    int v = blockIdx.x, t = threadIdx.x;
    __shared__ float x[NODE_IN_F], tm[H];
    const float* row = nf + (size_t)v * NODE_IN_F;
    x[t] = row[t];
    x[t + 64] = row[t + 64];
    agg[(size_t)v * H + t] = 0.f;
    __syncthreads();
    float acc = b1[t];
    const float4* wr = (const float4*)(w1 + (size_t)t * NODE_IN_F);
    #pragma unroll
    for (int q = 0; q < NODE_IN_F / 4; ++q) acc += dot4(wr[q], *(const float4*)&x[q * 4]);
    tm[t] = fmaxf(acc, 0.f);
    __syncthreads();
    float acc2 = b2[t];
    const float4* wr2 = (const float4*)(w2 + (size_t)t * H);
    #pragma unroll
    for (int q = 0; q < H / 4; ++q) acc2 += dot4(wr2[q], *(const float4*)&tm[q * 4]);
    h[(size_t)v * H + t] = acc2;
    __syncthreads();
    x[t] = acc2;           // reuse x as h-row
    __syncthreads();
    float acc3 = 0.f;
    for (int i = 0; i < H; ++i) acc3 += x[i] * b2e[i * 64 + t];
    hb[(size_t)v * H + t] = acc3;
}

// ---------------- CSR build (src/dst static; rebuilt each launch) ----------------
__global__ void k_zero_cnt(int* __restrict__ cnt) {
    int i = blockIdx.x * 256 + threadIdx.x;
    if (i < V_N) cnt[i] = 0;
}
__global__ void k_csr_count(const int* __restrict__ src, int* __restrict__ cnt) {
    int e = blockIdx.x * 256 + threadIdx.x;
    if (e < E_N) atomicAdd(&cnt[src[e]], 1);
}
// single-block exclusive scan of cnt -> offs (V+1), cursor copy
__global__ __launch_bounds__(256) void k_csr_scan(
    const int* __restrict__ cnt, int* __restrict__ offs, int* __restrict__ cursor)
{
    __shared__ int part[256];
    int t = threadIdx.x;
    const int CH = 79;                  // 256*79 = 20224 >= V_N
    int s = 0;
    for (int i = 0; i < CH; ++i) {
        int idx = t * CH + i;
        if (idx < V_N) s += cnt[idx];
    }
    part[t] = s;
    __syncthreads();
    if (t == 0) {
        int run = 0;
        for (int i = 0; i < 256; ++i) { int v = part[i]; part[i] = run; run += v; }
    }
    __syncthreads();
    int run = part[t];
    for (int i = 0; i < CH; ++i) {
        int idx = t * CH + i;
        if (idx < V_N) { offs[idx] = run; cursor[idx] = run; run += cnt[idx]; }
    }
    if (t == 255) offs[V_N] = run;      // == E_N
}
__global__ void k_csr_scatter(
    const int* __restrict__ src, const int* __restrict__ dst,
    int* __restrict__ cursor, int* __restrict__ sortpos, int* __restrict__ dst_s)
{
    int e = blockIdx.x * 256 + threadIdx.x;
    if (e < E_N) {
        int p = atomicAdd(&cursor[src[e]], 1);
        sortpos[e] = p;
        dst_s[p] = dst[e];
    }
}

// g_s[sortpos[e]] = relu(ef[e] @ w_e1.T + b_e1) -> (E,128) bf16, src-sorted rows.
__global__ __launch_bounds__(256) void k_edge_g(
    const float* __restrict__ ef,
    const float* __restrict__ w1, const float* __restrict__ b1,
    const int* __restrict__ sortpos,
    unsigned short* __restrict__ g)
{
    int tid = threadIdx.x;
    int e0 = blockIdx.x * 32;
    int c = tid & 127, eg = tid >> 7;
    __shared__ float xe[32][132];
    __shared__ int sp_s[32];
    if (tid < 32) sp_s[tid] = sortpos[e0 + tid];
    for (int idx = tid; idx < 1024; idx += 256) {
        int e = idx >> 5, kq = idx & 31;
        float4 v = *(const float4*)(ef + (size_t)(e0 + e) * EDGE_IN_F + kq * 4);
        *(float4*)&xe[e][kq * 4] = v;
    }
    __syncthreads();
    float acc[16];
    #pragma unroll
    for (int j = 0; j < 16; ++j) acc[j] = b1[c];
    const float4* wr = (const float4*)(w1 + (size_t)c * EDGE_IN_F);
    for (int kb = 0; kb < EDGE_IN_F / 4; ++kb) {
        float4 w = wr[kb];
        #pragma unroll
        for (int j = 0; j < 16; ++j) {
            float4 x = *(const float4*)&xe[eg * 16 + j][kb * 4];
            acc[j] += dot4(w, x);
        }
    }
    #pragma unroll
    for (int j = 0; j < 16; ++j)
        g[(size_t)sp_s[eg * 16 + j] * EDGE_HID + c] = f2bf(fmaxf(acc[j], 0.f));
}

// w2rt2 layout: row r2 = c*2048 + k*16 + u  (c = o-chunk, u = o within chunk)
// holds w_e2[(i*64 + (c*16+u)) * 128 + k] over i in [0,64), bf16. 1 MB one-time.
__global__ __launch_bounds__(64) void k_w2rt(
    const float* __restrict__ w2, unsigned short* __restrict__ w2rt)
{
    int r2 = blockIdx.x, i = threadIdx.x;
    int c = r2 >> 11, k = (r2 >> 4) & 127, u = r2 & 15;
    int o = c * 16 + u;
    float v = w2[(size_t)(i * 64 + o) * EDGE_HID + k];
    w2rt[(size_t)r2 * 64 + i] = f2bf(v);
}

// Fused per-node message kernel v5. Block = 16 nodes, 512 threads (8 waves),
// LDS exactly 65,536 B (64 KiB) -> target 2 blocks/CU -> 4 waves/SIMD.
// R18 (v4, 69,632 B LDS) measured Occupancy 22.5% = 1 block/CU despite
// 2x69.6KB <= 160KB: workgroups >64 KiB appear to get exclusive residency
// (or granule rounding blocks the pair). v5 removes the k-pad (PSTR 136->128,
// P = 256 rows x 256 B) and replaces it with an XOR swizzle: each 16-B
// granule of row r lives at byte (b ^ ((r&7)<<4)); r&7 == m&7 on both the
// write and read sides, so the same involution applies and every
// ds_read_b128 returns the intended granule. Read banks 4*(q^(m&7)) ->
// 8-way aliasing, same level as the padded layout (1.27M conflicts).
// o in 4 chunks of 16: phase A: P[n][o_w][k] = sum_i h[v0+n][i]*W2[(i,o)][k];
// wave wv owns k-pairs [wv*8, wv*8+8) (MFMA 16x16x32, depth-2 pipelined B
// loads, packed (k,k+1) u32 swizzled ds_writes); barrier; phase B: wave wv
// owns nodes wv*2..+2: msg[e, c*16+m] = sum_k g_s[e,k]*P[n][m][k] via 4
// chained MFMAs per 16-edge group + hb bias + atomicAdd scatter to agg[dst].
__global__ __launch_bounds__(512) void k_msg2(
    const float* __restrict__ h,
    const unsigned short* __restrict__ g_s,
    const unsigned short* __restrict__ w2rt,
    const float* __restrict__ hb,
    const int* __restrict__ offs,
    const int* __restrict__ dst_s,
    float* __restrict__ agg)
{
    int tid = threadIdx.x;
    int wv = tid >> 6, lane = tid & 63;
    int m = lane & 15, q = lane >> 4;
    int v0 = blockIdx.x * NB;
    __shared__ unsigned short P[256 * 128];   // 65,536 B -> 2 blocks/CU
    unsigned short* Pl = P;
    unsigned sx = (unsigned)((m & 7) << 4);   // row-derived XOR (row&7 == m&7)

    // ---- prefetch phase-B edge data: 2 nodes per wave, held across all chunks
    int esA[2], dA[2];
    bf16x8 gA0[2], gA1[2], gA2[2], gA3[2];
    #pragma unroll
    for (int nn = 0; nn < 2; ++nn) {
        int vv = v0 + wv * 2 + nn;
        int es_ = offs[vv], ee_ = offs[vv + 1];
        esA[nn] = es_; dA[nn] = ee_ - es_;
        int j = es_ + m;
        if (j >= ee_) j = (ee_ > 0) ? ee_ - 1 : 0;
        const unsigned short* ga = g_s + (size_t)j * EDGE_HID + q * 8;
        gA0[nn] = *(const bf16x8*)(ga);
        gA1[nn] = *(const bf16x8*)(ga + 32);
        gA2[nn] = *(const bf16x8*)(ga + 64);
        gA3[nn] = *(const bf16x8*)(ga + 96);
    }

    // ---- phase-A A-fragments: h rows for 16 nodes (1 dense n-tile), fp32 -> bf16
    bf16x8 Ah0, Ah1;
#define PACK8(DST, XA, XB) { \
    DST[0] = (short)f2bf(XA.x); DST[1] = (short)f2bf(XA.y); \
    DST[2] = (short)f2bf(XA.z); DST[3] = (short)f2bf(XA.w); \
    DST[4] = (short)f2bf(XB.x); DST[5] = (short)f2bf(XB.y); \
    DST[6] = (short)f2bf(XB.z); DST[7] = (short)f2bf(XB.w); }
    {
        const float* hr0 = h + (size_t)(v0 + m) * H;
        float4 x0 = *(const float4*)(hr0 + q * 8);
        float4 x1 = *(const float4*)(hr0 + q * 8 + 4);
        float4 x2 = *(const float4*)(hr0 + 32 + q * 8);
        float4 x3 = *(const float4*)(hr0 + 32 + q * 8 + 4);
        PACK8(Ah0, x0, x1)
        PACK8(Ah1, x2, x3)
    }
#undef PACK8

// B-frag load for k-pair p (within chunk): (k0,i-half0),(k0,i-half1),(k1,i0),(k1,i1)
#define LB2(Bn, p_) { \
    const unsigned short* b_ = wb + (size_t)(p_) * 2048; \
    Bn##0 = *(const bf16x8*)(b_); \
    Bn##1 = *(const bf16x8*)(b_ + 32); \
    Bn##2 = *(const bf16x8*)(b_ + 1024); \
    Bn##3 = *(const bf16x8*)(b_ + 1056); }

// compute k-pair p: 4 dense MFMAs (2 k x 2 i-halves x 1 n-tile), pack (k,k+1)
// -> u32, 4 swizzled ds_write_b32. D: row = node (q*4+r), col = o_w (m).
// Row byte base = node*4096 + m*256; k-word byte = (p*4) ^ sx.
#define CP2(p_, Bn) { \
    f32x4 d00 = {0.f,0.f,0.f,0.f}, d10 = {0.f,0.f,0.f,0.f}; \
    d00 = __builtin_amdgcn_mfma_f32_16x16x32_bf16(Ah0, Bn##0, d00, 0, 0, 0); \
    d00 = __builtin_amdgcn_mfma_f32_16x16x32_bf16(Ah1, Bn##1, d00, 0, 0, 0); \
    d10 = __builtin_amdgcn_mfma_f32_16x16x32_bf16(Ah0, Bn##2, d10, 0, 0, 0); \
    d10 = __builtin_amdgcn_mfma_f32_16x16x32_bf16(Ah1, Bn##3, d10, 0, 0, 0); \
    char* pb_ = (char*)Pl + ((q * 4) * 16 + m) * 256 + (((unsigned)(p_) * 4u) ^ sx); \
    unsigned int pk_; \
    pk_ = (unsigned)f2bf(d00[0]) | ((unsigned)f2bf(d10[0]) << 16); *(unsigned int*)(pb_ +     0) = pk_; \
    pk_ = (unsigned)f2bf(d00[1]) | ((unsigned)f2bf(d10[1]) << 16); *(unsigned int*)(pb_ +  4096) = pk_; \
    pk_ = (unsigned)f2bf(d00[2]) | ((unsigned)f2bf(d10[2]) << 16); *(unsigned int*)(pb_ +  8192) = pk_; \
    pk_ = (unsigned)f2bf(d00[3]) | ((unsigned)f2bf(d10[3]) << 16); *(unsigned int*)(pb_ + 12288) = pk_; }

    for (int c = 0; c < 4; ++c) {
        __syncthreads();               // P safe to overwrite (phase B of c-1 done)
        // ---- phase A for chunk c: wave wv owns k-pairs [wv*8, wv*8+8)
        const unsigned short* wb = w2rt + (size_t)c * 131072 + m * 64 + q * 8;
        int pg = wv * 8;
        bf16x8 Bu0, Bu1, Bu2, Bu3, Bv0, Bv1, Bv2, Bv3;
        LB2(Bu, pg + 0)
        LB2(Bv, pg + 1)
        CP2(pg + 0, Bu) LB2(Bu, pg + 2)
        CP2(pg + 1, Bv) LB2(Bv, pg + 3)
        CP2(pg + 2, Bu) LB2(Bu, pg + 4)
        CP2(pg + 3, Bv) LB2(Bv, pg + 5)
        CP2(pg + 4, Bu) LB2(Bu, pg + 6)
        CP2(pg + 5, Bv) LB2(Bv, pg + 7)
        CP2(pg + 6, Bu)
        CP2(pg + 7, Bv)
        __syncthreads();
        // ---- phase B for chunk c: wave wv owns nodes wv*2, wv*2+1
        #pragma unroll
        for (int nn = 0; nn < 2; ++nn) {
            int d_ = dA[nn];
            if (d_ <= 0) continue;
            int n = wv * 2 + nn;
            int vv = v0 + n;
            float hbv = hb[(size_t)vv * H + c * 16 + m];
            const char* pr = (const char*)Pl + (n * 16 + m) * 256;
            bf16x8 Bf0 = *(const bf16x8*)(pr + (((unsigned)(q * 16)      ) ^ sx));
            bf16x8 Bf1 = *(const bf16x8*)(pr + (((unsigned)(64 + q * 16) ) ^ sx));
            bf16x8 Bf2 = *(const bf16x8*)(pr + (((unsigned)(128 + q * 16)) ^ sx));
            bf16x8 Bf3 = *(const bf16x8*)(pr + (((unsigned)(192 + q * 16)) ^ sx));
            bf16x8 a0 = gA0[nn], a1 = gA1[nn], a2 = gA2[nn], a3 = gA3[nn];
            int es_ = esA[nn];
            for (int t = 0; t < d_; t += 16) {
                if (t > 0) {
                    int j = es_ + t + m;
                    if (j >= es_ + d_) j = es_ + d_ - 1;
                    const unsigned short* ga = g_s + (size_t)j * EDGE_HID + q * 8;
                    a0 = *(const bf16x8*)(ga);
                    a1 = *(const bf16x8*)(ga + 32);
                    a2 = *(const bf16x8*)(ga + 64);
                    a3 = *(const bf16x8*)(ga + 96);
                }
                f32x4 dd = {0.f, 0.f, 0.f, 0.f};
                dd = __builtin_amdgcn_mfma_f32_16x16x32_bf16(a0, Bf0, dd, 0, 0, 0);
                dd = __builtin_amdgcn_mfma_f32_16x16x32_bf16(a1, Bf1, dd, 0, 0, 0);
                dd = __builtin_amdgcn_mfma_f32_16x16x32_bf16(a2, Bf2, dd, 0, 0, 0);
                dd = __builtin_amdgcn_mfma_f32_16x16x32_bf16(a3, Bf3, dd, 0, 0, 0);
                #pragma unroll
                for (int r = 0; r < 4; ++r) {
                    int erow = q * 4 + r;
                    if (t + erow < d_) {
                        atomicAdd(&agg[(size_t)dst_s[es_ + t + erow] * H + c * 16 + m],
                                  dd[r] + hbv);
                    }
                }
            }
        }
    }
#undef LB2
#undef CP2
}

// GRU over 16 nodes/block; x=relu(agg+b_conv); agg re-zeroed; epilogue: hb = newh @ b_e2
__global__ __launch_bounds__(256) void k_gru(
    float* __restrict__ agg, const float* __restrict__ b_conv,
    const float* __restrict__ w_ih, const float* __restrict__ w_hh,
    const float* __restrict__ b_ih, const float* __restrict__ b_hh,
    const float* __restrict__ b2e,
    float* __restrict__ h, float* __restrict__ hb)
{
    int tid = threadIdx.x;
    int o = tid & 63, grp = tid >> 6;
    int vbase = blockIdx.x * 16;
    __shared__ float xl[16][68], hl[16][68];
    for (int idx = tid; idx < 16 * 64; idx += 256) {
        int n = idx >> 6, i = idx & 63;
        size_t p = (size_t)(vbase + n) * H + i;
        float a = agg[p];
        agg[p] = 0.f;
        xl[n][i] = fmaxf(a + b_conv[i], 0.f);
        hl[n][i] = h[p];
    }
    __syncthreads();
    float gir[4], giz[4], gin[4], ghr[4], ghz[4], ghn[4];
    #pragma unroll
    for (int n = 0; n < 4; ++n) {
        gir[n] = b_ih[o];       ghr[n] = b_hh[o];
        giz[n] = b_ih[64 + o];  ghz[n] = b_hh[64 + o];
        gin[n] = b_ih[128 + o]; ghn[n] = b_hh[128 + o];
    }
    const float4* wir = (const float4*)(w_ih + (size_t)o * H);
    const float4* wiz = (const float4*)(w_ih + (size_t)(64 + o) * H);
    const float4* win = (const float4*)(w_ih + (size_t)(128 + o) * H);
    const float4* whr = (const float4*)(w_hh + (size_t)o * H);
    const float4* whz = (const float4*)(w_hh + (size_t)(64 + o) * H);
    const float4* whn = (const float4*)(w_hh + (size_t)(128 + o) * H);
    #pragma unroll 4
    for (int qq = 0; qq < H / 4; ++qq) {
        float4 a1 = wir[qq], a2 = wiz[qq], a3 = win[qq];
        float4 c1 = whr[qq], c2 = whz[qq], c3 = whn[qq];
        #pragma unroll
        for (int n = 0; n < 4; ++n) {
            float4 xv = *(const float4*)&xl[grp * 4 + n][qq * 4];
            float4 hv = *(const float4*)&hl[grp * 4 + n][qq * 4];
            gir[n] += dot4(a1, xv); giz[n] += dot4(a2, xv); gin[n] += dot4(a3, xv);
            ghr[n] += dot4(c1, hv); ghz[n] += dot4(c2, hv); ghn[n] += dot4(c3, hv);
        }
    }
    float newh[4];
    #pragma unroll
    for (int n = 0; n < 4; ++n) {
        float hv = hl[grp * 4 + n][o];
        float r = 1.f / (1.f + __expf(-(gir[n] + ghr[n])));
        float z = 1.f / (1.f + __expf(-(giz[n] + ghz[n])));
        float na = gin[n] + r * ghn[n];
        float tn = 1.f - 2.f / (__expf(2.f * na) + 1.f);   // tanh
        newh[n] = (1.f - z) * tn + z * hv;
        h[(size_t)(vbase + grp * 4 + n) * H + o] = newh[n];
    }
    __syncthreads();                 // xl dead; reuse for new h
    #pragma unroll
    for (int n = 0; n < 4; ++n) xl[grp * 4 + n][o] = newh[n];
    __syncthreads();
    float hbacc[4] = {0.f, 0.f, 0.f, 0.f};
    for (int i = 0; i < H; ++i) {
        float w = b2e[i * 64 + o];
        #pragma unroll
        for (int n = 0; n < 4; ++n) hbacc[n] += xl[grp * 4 + n][i] * w;
    }
    #pragma unroll
    for (int n = 0; n < 4; ++n)
        hb[(size_t)(vbase + grp * 4 + n) * H + o] = hbacc[n];
}

// out = relu(h @ w_d1.T + b_d1) @ w_d2.T + b_d2  -> fp32
__global__ __launch_bounds__(64) void k_decoder(
    const float* __restrict__ h,
    const float* __restrict__ w1, const float* __restrict__ b1,
    const float* __restrict__ w2, const float* __restrict__ b2,
    float* __restrict__ out)
{
    int v = blockIdx.x, t = threadIdx.x;
    __shared__ float hl[H], tl[H];
    hl[t] = h[(size_t)v * H + t];
    __syncthreads();
    float acc = b1[t];
    const float4* wr = (const float4*)(w1 + (size_t)t * H);
    #pragma unroll
    for (int q = 0; q < H / 4; ++q) acc += dot4(wr[q], *(const float4*)&hl[q * 4]);
    tl[t] = fmaxf(acc, 0.f);
    __syncthreads();
    float acc2 = b2[t];
    const float4* wr2 = (const float4*)(w2 + (size_t)t * H);
    #pragma unroll
    for (int q = 0; q < H / 4; ++q) acc2 += dot4(wr2[q], *(const float4*)&tl[q * 4]);
    out[(size_t)v * OUT_F + t] = acc2;
}

extern "C" void kernel_launch(void* const* d_in, const int* in_sizes, int n_in,
                              void* d_out, int out_size, void* d_ws, size_t ws_size,
                              hipStream_t stream) {
    const float* nf     = (const float*)d_in[0];
    const float* ef     = (const float*)d_in[1];
    const int* src      = (const int*)d_in[2];
    const int* dst      = (const int*)d_in[3];
    const float* w_p1   = (const float*)d_in[4];
    const float* b_p1   = (const float*)d_in[5];
    const float* w_p2   = (const float*)d_in[6];
    const float* b_p2   = (const float*)d_in[7];
    const float* w_e1   = (const float*)d_in[8];
    const float* b_e1   = (const float*)d_in[9];
    const float* w_e2   = (const float*)d_in[10];
    const float* b_e2   = (const float*)d_in[11];
    const float* b_conv = (const float*)d_in[12];
    const float* w_ih   = (const float*)d_in[13];
    const float* w_hh   = (const float*)d_in[14];
    const float* b_ih   = (const float*)d_in[15];
    const float* b_hh   = (const float*)d_in[16];
    const float* w_d1   = (const float*)d_in[17];
    const float* b_d1   = (const float*)d_in[18];
    const float* w_d2   = (const float*)d_in[19];
    const float* b_d2   = (const float*)d_in[20];

    // d_ws layout (total 42,008,576 B):
    //   g_s     : E*128 bf16 (src-sorted rows)      @ 0          25,600,000
    //   w2rt2   : 8192*64 bf16 (chunked reindex)    @ 25,600,000  1,048,576
    //   h       : V*64 f32                          @ 26,648,576  5,120,000
    //   agg     : V*64 f32                          @ 31,768,576  5,120,000
    //   hb      : V*64 f32                          @ 36,888,576  5,120,000
    char* ws = (char*)d_ws;
    unsigned short* g_s  = (unsigned short*)(ws);
    unsigned short* w2rt = (unsigned short*)(ws + 25600000LL);
    float* h             = (float*)(ws + 26648576LL);
    float* agg           = (float*)(ws + 31768576LL);
    float* hb            = (float*)(ws + 36888576LL);

    // CSR scratch lives in d_out (5,120,000 B; fully overwritten by k_decoder
    // at the end, so it is legal intra-launch scratch). Total used: 1,040,016 B.
    char* ob = (char*)d_out;
    int* offs            = (int*)(ob);               //   80,016 B ((V+1) i32, padded)
    int* cursor          = (int*)(ob +   80016LL);   //   80,000 B
    int* cnt             = (int*)(ob +  160016LL);   //   80,000 B
    int* sortpos         = (int*)(ob +  240016LL);   //  400,000 B
    int* dst_s           = (int*)(ob +  640016LL);   //  400,000 B

    k_project<<<V_N, 64, 0, stream>>>(nf, w_p1, b_p1, w_p2, b_p2, b_e2, h, agg, hb);
    k_zero_cnt<<<(V_N + 255) / 256, 256, 0, stream>>>(cnt);
    k_csr_count<<<(E_N + 255) / 256, 256, 0, stream>>>(src, cnt);
    k_csr_scan<<<1, 256, 0, stream>>>(cnt, offs, cursor);
    k_csr_scatter<<<(E_N + 255) / 256, 256, 0, stream>>>(src, dst, cursor, sortpos, dst_s);
    k_edge_g<<<E_N / 32, 256, 0, stream>>>(ef, w_e1, b_e1, sortpos, g_s);
    k_w2rt<<<8192, 64, 0, stream>>>(w_e2, w2rt);
    for (int s = 0; s < STEPS; ++s) {
        k_msg2<<<V_N / NB, 512, 0, stream>>>(h, g_s, w2rt, hb, offs, dst_s, agg);
        k_gru<<<V_N / 16, 256, 0, stream>>>(agg, b_conv, w_ih, w_hh, b_ih, b_hh, b_e2, h, hb);
    }
    k_decoder<<<V_N, 64, 0, stream>>>(h, w_d1, b_d1, w_d2, b_d2, (float*)d_out);
}

// Round 21
// 2531.215 us; speedup vs baseline: 1.1827x; 1.1778x over previous
//
#include <hip/hip_runtime.h>

#define V_N 20000
#define E_N 100000
#define NODE_IN_F 128
#define EDGE_IN_F 128
#define H 64
#define EDGE_HID 128
#define OUT_F 64
#define STEPS 9

#define NB 32       // nodes per k_msg2 block (o-split into 4 chunks of 16)
#define PSTR 136    // P k-stride in shorts (128 + 8 pad) -> row 272 B, 16B-aligned
#define GNB 64      // nodes per k_gru block

typedef __attribute__((ext_vector_type(8))) short bf16x8;
typedef __attribute__((ext_vector_type(4))) float f32x4;

__device__ __forceinline__ unsigned short f2bf(float f) {
    union { float f; unsigned int u; } v; v.f = f;
    unsigned int u = v.u;
    unsigned int r = (u + 0x7fffu + ((u >> 16) & 1u)) >> 16;  // RNE
    return (unsigned short)r;
}

__device__ __forceinline__ float dot4(float4 w, float4 x) {
    return w.x * x.x + w.y * x.y + w.z * x.z + w.w * x.w;
}

// h0 = relu(nf@w1.T+b1)@w2.T+b2 (V,64) fp32; zero agg; hb = h0-row @ b_e2-matrix
__global__ __launch_bounds__(64) void k_project(
    const float* __restrict__ nf,
    const float* __restrict__ w1, const float* __restrict__ b1,
    const float* __restrict__ w2, const float* __restrict__ b2,
    const float* __restrict__ b2e,
    float* __restrict__ h, float* __restrict__ agg, float* __restrict__ hb)
{
    int v = blockIdx.x, t = threadIdx.x;
    __shared__ float x[NODE_IN_F], tm[H];
    const float* row = nf + (size_t)v * NODE_IN_F;
    x[t] = row[t];
    x[t + 64] = row[t + 64];
    agg[(size_t)v * H + t] = 0.f;
    __syncthreads();
    float acc = b1[t];
    const float4* wr = (const float4*)(w1 + (size_t)t * NODE_IN_F);
    #pragma unroll
    for (int q = 0; q < NODE_IN_F / 4; ++q) acc += dot4(wr[q], *(const float4*)&x[q * 4]);
    tm[t] = fmaxf(acc, 0.f);
    __syncthreads();
    float acc2 = b2[t];
    const float4* wr2 = (const float4*)(w2 + (size_t)t * H);
    #pragma unroll
    for (int q = 0; q < H / 4; ++q) acc2 += dot4(wr2[q], *(const float4*)&tm[q * 4]);
    h[(size_t)v * H + t] = acc2;
    __syncthreads();
    x[t] = acc2;           // reuse x as h-row
    __syncthreads();
    float acc3 = 0.f;
    for (int i = 0; i < H; ++i) acc3 += x[i] * b2e[i * 64 + t];
    hb[(size_t)v * H + t] = acc3;
}

// ---------------- CSR build (src/dst static; rebuilt each launch) ----------------
__global__ void k_zero_cnt(int* __restrict__ cnt) {
    int i = blockIdx.x * 256 + threadIdx.x;
    if (i < V_N) cnt[i] = 0;
}
__global__ void k_csr_count(const int* __restrict__ src, int* __restrict__ cnt) {
    int e = blockIdx.x * 256 + threadIdx.x;
    if (e < E_N) atomicAdd(&cnt[src[e]], 1);
}
// single-block exclusive scan of cnt -> offs (V+1), cursor copy
__global__ __launch_bounds__(256) void k_csr_scan(
    const int* __restrict__ cnt, int* __restrict__ offs, int* __restrict__ cursor)
{
    __shared__ int part[256];
    int t = threadIdx.x;
    const int CH = 79;                  // 256*79 = 20224 >= V_N
    int s = 0;
    for (int i = 0; i < CH; ++i) {
        int idx = t * CH + i;
        if (idx < V_N) s += cnt[idx];
    }
    part[t] = s;
    __syncthreads();
    if (t == 0) {
        int run = 0;
        for (int i = 0; i < 256; ++i) { int v = part[i]; part[i] = run; run += v; }
    }
    __syncthreads();
    int run = part[t];
    for (int i = 0; i < CH; ++i) {
        int idx = t * CH + i;
        if (idx < V_N) { offs[idx] = run; cursor[idx] = run; run += cnt[idx]; }
    }
    if (t == 255) offs[V_N] = run;      // == E_N
}
__global__ void k_csr_scatter(
    const int* __restrict__ src, const int* __restrict__ dst,
    int* __restrict__ cursor, int* __restrict__ sortpos, int* __restrict__ dst_s)
{
    int e = blockIdx.x * 256 + threadIdx.x;
    if (e < E_N) {
        int p = atomicAdd(&cursor[src[e]], 1);
        sortpos[e] = p;
        dst_s[p] = dst[e];
    }
}

// g_s[sortpos[e]] = relu(ef[e] @ w_e1.T + b_e1) -> (E,128) bf16, src-sorted rows.
__global__ __launch_bounds__(256) void k_edge_g(
    const float* __restrict__ ef,
    const float* __restrict__ w1, const float* __restrict__ b1,
    const int* __restrict__ sortpos,
    unsigned short* __restrict__ g)
{
    int tid = threadIdx.x;
    int e0 = blockIdx.x * 32;
    int c = tid & 127, eg = tid >> 7;
    __shared__ float xe[32][132];
    __shared__ int sp_s[32];
    if (tid < 32) sp_s[tid] = sortpos[e0 + tid];
    for (int idx = tid; idx < 1024; idx += 256) {
        int e = idx >> 5, kq = idx & 31;
        float4 v = *(const float4*)(ef + (size_t)(e0 + e) * EDGE_IN_F + kq * 4);
        *(float4*)&xe[e][kq * 4] = v;
    }
    __syncthreads();
    float acc[16];
    #pragma unroll
    for (int j = 0; j < 16; ++j) acc[j] = b1[c];
    const float4* wr = (const float4*)(w1 + (size_t)c * EDGE_IN_F);
    for (int kb = 0; kb < EDGE_IN_F / 4; ++kb) {
        float4 w = wr[kb];
        #pragma unroll
        for (int j = 0; j < 16; ++j) {
            float4 x = *(const float4*)&xe[eg * 16 + j][kb * 4];
            acc[j] += dot4(w, x);
        }
    }
    #pragma unroll
    for (int j = 0; j < 16; ++j)
        g[(size_t)sp_s[eg * 16 + j] * EDGE_HID + c] = f2bf(fmaxf(acc[j], 0.f));
}

// w2rt2 layout: row r2 = c*2048 + k*16 + u  (c = o-chunk, u = o within chunk)
// holds w_e2[(i*64 + (c*16+u)) * 128 + k] over i in [0,64), bf16. 1 MB one-time.
__global__ __launch_bounds__(64) void k_w2rt(
    const float* __restrict__ w2, unsigned short* __restrict__ w2rt)
{
    int r2 = blockIdx.x, i = threadIdx.x;
    int c = r2 >> 11, k = (r2 >> 4) & 127, u = r2 & 15;
    int o = c * 16 + u;
    float v = w2[(size_t)(i * 64 + o) * EDGE_HID + k];
    w2rt[(size_t)r2 * 64 + i] = f2bf(v);
}

// Fused per-node message kernel (R7-measured best: 176 us, VGPR 88, no spills).
// Block = 32 nodes, 512 threads (8 waves), 1 block/CU (139 KB LDS).
// o in 4 chunks of 16: phase A: P[n][o_w][k] = sum_i h[v0+n][i]*W2[(i,o)][k];
// wave wv owns k-pairs [wv*8, wv*8+8) (MFMA 16x16x32, 2 dense n-tiles, depth-2
// pipelined B loads, packed (k,k+1) u32 ds_writes); barrier; phase B: wave wv
// owns nodes wv*4..+4: msg[e, c*16+m] = sum_k g_s[e,k]*P[n][m][k] via 4 chained
// MFMAs per 16-edge group + hb bias + atomicAdd scatter to agg[dst].
// NOTE: occupancy experiments (R13-R19: 1024 threads, 69.6KB, 64KB LDS) all
// failed to raise residency past 1 block/CU or introduced spills; this config
// is the measured optimum of the family.
__global__ __launch_bounds__(512) void k_msg2(
    const float* __restrict__ h,
    const unsigned short* __restrict__ g_s,
    const unsigned short* __restrict__ w2rt,
    const float* __restrict__ hb,
    const int* __restrict__ offs,
    const int* __restrict__ dst_s,
    float* __restrict__ agg)
{
    int tid = threadIdx.x;
    int wv = tid >> 6, lane = tid & 63;
    int m = lane & 15, q = lane >> 4;
    int v0 = blockIdx.x * NB;
    __shared__ unsigned short P[512 * PSTR];   // 139,264 B
    unsigned short* Pl = P;

    // ---- prefetch phase-B edge data: 4 nodes per wave, held across all chunks
    int esA[4], dA[4];
    bf16x8 gA0[4], gA1[4], gA2[4], gA3[4];
    #pragma unroll
    for (int nn = 0; nn < 4; ++nn) {
        int vv = v0 + wv * 4 + nn;
        int es_ = offs[vv], ee_ = offs[vv + 1];
        esA[nn] = es_; dA[nn] = ee_ - es_;
        int j = es_ + m;
        if (j >= ee_) j = (ee_ > 0) ? ee_ - 1 : 0;
        const unsigned short* ga = g_s + (size_t)j * EDGE_HID + q * 8;
        gA0[nn] = *(const bf16x8*)(ga);
        gA1[nn] = *(const bf16x8*)(ga + 32);
        gA2[nn] = *(const bf16x8*)(ga + 64);
        gA3[nn] = *(const bf16x8*)(ga + 96);
    }

    // ---- phase-A A-fragments: h rows for 32 nodes (2 n-tiles), fp32 -> bf16
    bf16x8 Ah00, Ah01, Ah10, Ah11;
#define PACK8(DST, XA, XB) { \
    DST[0] = (short)f2bf(XA.x); DST[1] = (short)f2bf(XA.y); \
    DST[2] = (short)f2bf(XA.z); DST[3] = (short)f2bf(XA.w); \
    DST[4] = (short)f2bf(XB.x); DST[5] = (short)f2bf(XB.y); \
    DST[6] = (short)f2bf(XB.z); DST[7] = (short)f2bf(XB.w); }
    {
        const float* hr0 = h + (size_t)(v0 + m) * H;
        float4 x0 = *(const float4*)(hr0 + q * 8);
        float4 x1 = *(const float4*)(hr0 + q * 8 + 4);
        float4 x2 = *(const float4*)(hr0 + 32 + q * 8);
        float4 x3 = *(const float4*)(hr0 + 32 + q * 8 + 4);
        PACK8(Ah00, x0, x1)
        PACK8(Ah01, x2, x3)
        const float* hr1 = h + (size_t)(v0 + 16 + m) * H;
        float4 y0 = *(const float4*)(hr1 + q * 8);
        float4 y1 = *(const float4*)(hr1 + q * 8 + 4);
        float4 y2 = *(const float4*)(hr1 + 32 + q * 8);
        float4 y3 = *(const float4*)(hr1 + 32 + q * 8 + 4);
        PACK8(Ah10, y0, y1)
        PACK8(Ah11, y2, y3)
    }
#undef PACK8

// B-frag load for k-pair p (global within chunk): 4 frags (k0,i0),(k0,i1),(k1,i0),(k1,i1)
#define LB2(Bn, p_) { \
    const unsigned short* b_ = wb + (size_t)(p_) * 2048; \
    Bn##0 = *(const bf16x8*)(b_); \
    Bn##1 = *(const bf16x8*)(b_ + 32); \
    Bn##2 = *(const bf16x8*)(b_ + 1024); \
    Bn##3 = *(const bf16x8*)(b_ + 1056); }

// compute k-pair p: 8 dense MFMAs (2 k x 2 n-tiles x 2 i-halves), pack (k,k+1)
// -> u32, 8 ds_write_b32. D: row = node-sub (q*4+r), col = o_w (m).
#define CP2(p_, Bn) { \
    f32x4 d00 = {0.f,0.f,0.f,0.f}, d10 = {0.f,0.f,0.f,0.f}; \
    f32x4 d01 = {0.f,0.f,0.f,0.f}, d11 = {0.f,0.f,0.f,0.f}; \
    d00 = __builtin_amdgcn_mfma_f32_16x16x32_bf16(Ah00, Bn##0, d00, 0, 0, 0); \
    d00 = __builtin_amdgcn_mfma_f32_16x16x32_bf16(Ah01, Bn##1, d00, 0, 0, 0); \
    d10 = __builtin_amdgcn_mfma_f32_16x16x32_bf16(Ah00, Bn##2, d10, 0, 0, 0); \
    d10 = __builtin_amdgcn_mfma_f32_16x16x32_bf16(Ah01, Bn##3, d10, 0, 0, 0); \
    d01 = __builtin_amdgcn_mfma_f32_16x16x32_bf16(Ah10, Bn##0, d01, 0, 0, 0); \
    d01 = __builtin_amdgcn_mfma_f32_16x16x32_bf16(Ah11, Bn##1, d01, 0, 0, 0); \
    d11 = __builtin_amdgcn_mfma_f32_16x16x32_bf16(Ah10, Bn##2, d11, 0, 0, 0); \
    d11 = __builtin_amdgcn_mfma_f32_16x16x32_bf16(Ah11, Bn##3, d11, 0, 0, 0); \
    unsigned short* pw_ = Pl + (size_t)((q * 4) * 16 + m) * PSTR + (p_) * 2; \
    unsigned int pk_; \
    pk_ = (unsigned)f2bf(d00[0]) | ((unsigned)f2bf(d10[0]) << 16); *(unsigned int*)(pw_ +     0) = pk_; \
    pk_ = (unsigned)f2bf(d00[1]) | ((unsigned)f2bf(d10[1]) << 16); *(unsigned int*)(pw_ +  2176) = pk_; \
    pk_ = (unsigned)f2bf(d00[2]) | ((unsigned)f2bf(d10[2]) << 16); *(unsigned int*)(pw_ +  4352) = pk_; \
    pk_ = (unsigned)f2bf(d00[3]) | ((unsigned)f2bf(d10[3]) << 16); *(unsigned int*)(pw_ +  6528) = pk_; \
    pk_ = (unsigned)f2bf(d01[0]) | ((unsigned)f2bf(d11[0]) << 16); *(unsigned int*)(pw_ + 34816) = pk_; \
    pk_ = (unsigned)f2bf(d01[1]) | ((unsigned)f2bf(d11[1]) << 16); *(unsigned int*)(pw_ + 36992) = pk_; \
    pk_ = (unsigned)f2bf(d01[2]) | ((unsigned)f2bf(d11[2]) << 16); *(unsigned int*)(pw_ + 39168) = pk_; \
    pk_ = (unsigned)f2bf(d01[3]) | ((unsigned)f2bf(d11[3]) << 16); *(unsigned int*)(pw_ + 41344) = pk_; }

    for (int c = 0; c < 4; ++c) {
        __syncthreads();               // P safe to overwrite (phase B of c-1 done)
        // ---- phase A for chunk c: wave wv owns k-pairs [wv*8, wv*8+8)
        const unsigned short* wb = w2rt + (size_t)c * 131072 + m * 64 + q * 8;
        int pg = wv * 8;
        bf16x8 Bu0, Bu1, Bu2, Bu3, Bv0, Bv1, Bv2, Bv3;
        LB2(Bu, pg + 0)
        LB2(Bv, pg + 1)
        CP2(pg + 0, Bu) LB2(Bu, pg + 2)
        CP2(pg + 1, Bv) LB2(Bv, pg + 3)
        CP2(pg + 2, Bu) LB2(Bu, pg + 4)
        CP2(pg + 3, Bv) LB2(Bv, pg + 5)
        CP2(pg + 4, Bu) LB2(Bu, pg + 6)
        CP2(pg + 5, Bv) LB2(Bv, pg + 7)
        CP2(pg + 6, Bu)
        CP2(pg + 7, Bv)
        __syncthreads();
        // ---- phase B for chunk c: wave wv owns nodes wv*4 .. wv*4+4
        #pragma unroll
        for (int nn = 0; nn < 4; ++nn) {
            int d_ = dA[nn];
            if (d_ <= 0) continue;
            int n = wv * 4 + nn;
            int vv = v0 + n;
            float hbv = hb[(size_t)vv * H + c * 16 + m];
            const unsigned short* pr = Pl + (size_t)(n * 16 + m) * PSTR + q * 8;
            bf16x8 Bf0 = *(const bf16x8*)(pr);
            bf16x8 Bf1 = *(const bf16x8*)(pr + 32);
            bf16x8 Bf2 = *(const bf16x8*)(pr + 64);
            bf16x8 Bf3 = *(const bf16x8*)(pr + 96);
            bf16x8 a0 = gA0[nn], a1 = gA1[nn], a2 = gA2[nn], a3 = gA3[nn];
            int es_ = esA[nn];
            for (int t = 0; t < d_; t += 16) {
                if (t > 0) {
                    int j = es_ + t + m;
                    if (j >= es_ + d_) j = es_ + d_ - 1;
                    const unsigned short* ga = g_s + (size_t)j * EDGE_HID + q * 8;
                    a0 = *(const bf16x8*)(ga);
                    a1 = *(const bf16x8*)(ga + 32);
                    a2 = *(const bf16x8*)(ga + 64);
                    a3 = *(const bf16x8*)(ga + 96);
                }
                f32x4 dd = {0.f, 0.f, 0.f, 0.f};
                dd = __builtin_amdgcn_mfma_f32_16x16x32_bf16(a0, Bf0, dd, 0, 0, 0);
                dd = __builtin_amdgcn_mfma_f32_16x16x32_bf16(a1, Bf1, dd, 0, 0, 0);
                dd = __builtin_amdgcn_mfma_f32_16x16x32_bf16(a2, Bf2, dd, 0, 0, 0);
                dd = __builtin_amdgcn_mfma_f32_16x16x32_bf16(a3, Bf3, dd, 0, 0, 0);
                #pragma unroll
                for (int r = 0; r < 4; ++r) {
                    int erow = q * 4 + r;
                    if (t + erow < d_) {
                        atomicAdd(&agg[(size_t)dst_s[es_ + t + erow] * H + c * 16 + m],
                                  dd[r] + hbv);
                    }
                }
            }
        }
    }
#undef LB2
#undef CP2
}

// GRU v2: 64 nodes/block, 512 threads (8 o-groups x 8 nodes each).
// R19 analysis: old 16-node/256-thread k_gru had 4x-redundant weight reads
// (491 MB L2/dispatch) across 1250 tiny blocks, latency-bound at ~86 us/step.
// 8 nodes per thread amortizes each 1536-B weight row-set 2x better and cuts
// blocks to 313 (fully resident in ~1 scheduling round).
// x=relu(agg+b_conv); agg re-zeroed; epilogue: hb = newh @ b_e2.
__global__ __launch_bounds__(512) void k_gru(
    float* __restrict__ agg, const float* __restrict__ b_conv,
    const float* __restrict__ w_ih, const float* __restrict__ w_hh,
    const float* __restrict__ b_ih, const float* __restrict__ b_hh,
    const float* __restrict__ b2e,
    float* __restrict__ h, float* __restrict__ hb)
{
    int tid = threadIdx.x;
    int o = tid & 63, grp = tid >> 6;          // 8 groups of 8 nodes
    int vbase = blockIdx.x * GNB;
    __shared__ float xl[GNB][68], hl[GNB][68]; // 2 x 17,408 B = 34,816 B
    for (int idx = tid; idx < GNB * 64; idx += 512) {
        int n = idx >> 6, i = idx & 63;
        int v = vbase + n;
        float a = 0.f, hv = 0.f;
        if (v < V_N) {
            size_t p = (size_t)v * H + i;
            a = fmaxf(agg[p] + b_conv[i], 0.f);
            agg[p] = 0.f;
            hv = h[p];
        }
        xl[n][i] = a;
        hl[n][i] = hv;
    }
    __syncthreads();
    float gir[8], giz[8], gin[8], ghr[8], ghz[8], ghn[8];
    #pragma unroll
    for (int n = 0; n < 8; ++n) {
        gir[n] = b_ih[o];       ghr[n] = b_hh[o];
        giz[n] = b_ih[64 + o];  ghz[n] = b_hh[64 + o];
        gin[n] = b_ih[128 + o]; ghn[n] = b_hh[128 + o];
    }
    const float4* wir = (const float4*)(w_ih + (size_t)o * H);
    const float4* wiz = (const float4*)(w_ih + (size_t)(64 + o) * H);
    const float4* win = (const float4*)(w_ih + (size_t)(128 + o) * H);
    const float4* whr = (const float4*)(w_hh + (size_t)o * H);
    const float4* whz = (const float4*)(w_hh + (size_t)(64 + o) * H);
    const float4* whn = (const float4*)(w_hh + (size_t)(128 + o) * H);
    for (int qq = 0; qq < H / 4; ++qq) {
        float4 a1 = wir[qq], a2 = wiz[qq], a3 = win[qq];
        float4 c1 = whr[qq], c2 = whz[qq], c3 = whn[qq];
        #pragma unroll
        for (int n = 0; n < 8; ++n) {
            float4 xv = *(const float4*)&xl[grp * 8 + n][qq * 4];
            float4 hv = *(const float4*)&hl[grp * 8 + n][qq * 4];
            gir[n] += dot4(a1, xv); giz[n] += dot4(a2, xv); gin[n] += dot4(a3, xv);
            ghr[n] += dot4(c1, hv); ghz[n] += dot4(c2, hv); ghn[n] += dot4(c3, hv);
        }
    }
    float newh[8];
    #pragma unroll
    for (int n = 0; n < 8; ++n) {
        float hv = hl[grp * 8 + n][o];
        float r = 1.f / (1.f + __expf(-(gir[n] + ghr[n])));
        float z = 1.f / (1.f + __expf(-(giz[n] + ghz[n])));
        float na = gin[n] + r * ghn[n];
        float tn = 1.f - 2.f / (__expf(2.f * na) + 1.f);   // tanh
        newh[n] = (1.f - z) * tn + z * hv;
        int v = vbase + grp * 8 + n;
        if (v < V_N) h[(size_t)v * H + o] = newh[n];
    }
    __syncthreads();                 // xl dead; reuse for new h
    #pragma unroll
    for (int n = 0; n < 8; ++n) xl[grp * 8 + n][o] = newh[n];
    __syncthreads();
    float hbacc[8] = {0.f, 0.f, 0.f, 0.f, 0.f, 0.f, 0.f, 0.f};
    for (int i = 0; i < H; ++i) {
        float w = b2e[i * 64 + o];
        #pragma unroll
        for (int n = 0; n < 8; ++n) hbacc[n] += xl[grp * 8 + n][i] * w;
    }
    #pragma unroll
    for (int n = 0; n < 8; ++n) {
        int v = vbase + grp * 8 + n;
        if (v < V_N) hb[(size_t)v * H + o] = hbacc[n];
    }
}

// out = relu(h @ w_d1.T + b_d1) @ w_d2.T + b_d2  -> fp32
__global__ __launch_bounds__(64) void k_decoder(
    const float* __restrict__ h,
    const float* __restrict__ w1, const float* __restrict__ b1,
    const float* __restrict__ w2, const float* __restrict__ b2,
    float* __restrict__ out)
{
    int v = blockIdx.x, t = threadIdx.x;
    __shared__ float hl[H], tl[H];
    hl[t] = h[(size_t)v * H + t];
    __syncthreads();
    float acc = b1[t];
    const float4* wr = (const float4*)(w1 + (size_t)t * H);
    #pragma unroll
    for (int q = 0; q < H / 4; ++q) acc += dot4(wr[q], *(const float4*)&hl[q * 4]);
    tl[t] = fmaxf(acc, 0.f);
    __syncthreads();
    float acc2 = b2[t];
    const float4* wr2 = (const float4*)(w2 + (size_t)t * H);
    #pragma unroll
    for (int q = 0; q < H / 4; ++q) acc2 += dot4(wr2[q], *(const float4*)&tl[q * 4]);
    out[(size_t)v * OUT_F + t] = acc2;
}

extern "C" void kernel_launch(void* const* d_in, const int* in_sizes, int n_in,
                              void* d_out, int out_size, void* d_ws, size_t ws_size,
                              hipStream_t stream) {
    const float* nf     = (const float*)d_in[0];
    const float* ef     = (const float*)d_in[1];
    const int* src      = (const int*)d_in[2];
    const int* dst      = (const int*)d_in[3];
    const float* w_p1   = (const float*)d_in[4];
    const float* b_p1   = (const float*)d_in[5];
    const float* w_p2   = (const float*)d_in[6];
    const float* b_p2   = (const float*)d_in[7];
    const float* w_e1   = (const float*)d_in[8];
    const float* b_e1   = (const float*)d_in[9];
    const float* w_e2   = (const float*)d_in[10];
    const float* b_e2   = (const float*)d_in[11];
    const float* b_conv = (const float*)d_in[12];
    const float* w_ih   = (const float*)d_in[13];
    const float* w_hh   = (const float*)d_in[14];
    const float* b_ih   = (const float*)d_in[15];
    const float* b_hh   = (const float*)d_in[16];
    const float* w_d1   = (const float*)d_in[17];
    const float* b_d1   = (const float*)d_in[18];
    const float* w_d2   = (const float*)d_in[19];
    const float* b_d2   = (const float*)d_in[20];

    // d_ws layout (total 42,008,576 B):
    //   g_s     : E*128 bf16 (src-sorted rows)      @ 0          25,600,000
    //   w2rt2   : 8192*64 bf16 (chunked reindex)    @ 25,600,000  1,048,576
    //   h       : V*64 f32                          @ 26,648,576  5,120,000
    //   agg     : V*64 f32                          @ 31,768,576  5,120,000
    //   hb      : V*64 f32                          @ 36,888,576  5,120,000
    char* ws = (char*)d_ws;
    unsigned short* g_s  = (unsigned short*)(ws);
    unsigned short* w2rt = (unsigned short*)(ws + 25600000LL);
    float* h             = (float*)(ws + 26648576LL);
    float* agg           = (float*)(ws + 31768576LL);
    float* hb            = (float*)(ws + 36888576LL);

    // CSR scratch lives in d_out (5,120,000 B; fully overwritten by k_decoder
    // at the end, so it is legal intra-launch scratch). Total used: 1,040,016 B.
    char* ob = (char*)d_out;
    int* offs            = (int*)(ob);               //   80,016 B ((V+1) i32, padded)
    int* cursor          = (int*)(ob +   80016LL);   //   80,000 B
    int* cnt             = (int*)(ob +  160016LL);   //   80,000 B
    int* sortpos         = (int*)(ob +  240016LL);   //  400,000 B
    int* dst_s           = (int*)(ob +  640016LL);   //  400,000 B

    k_project<<<V_N, 64, 0, stream>>>(nf, w_p1, b_p1, w_p2, b_p2, b_e2, h, agg, hb);
    k_zero_cnt<<<(V_N + 255) / 256, 256, 0, stream>>>(cnt);
    k_csr_count<<<(E_N + 255) / 256, 256, 0, stream>>>(src, cnt);
    k_csr_scan<<<1, 256, 0, stream>>>(cnt, offs, cursor);
    k_csr_scatter<<<(E_N + 255) / 256, 256, 0, stream>>>(src, dst, cursor, sortpos, dst_s);
    k_edge_g<<<E_N / 32, 256, 0, stream>>>(ef, w_e1, b_e1, sortpos, g_s);
    k_w2rt<<<8192, 64, 0, stream>>>(w_e2, w2rt);
    for (int s = 0; s < STEPS; ++s) {
        k_msg2<<<V_N / NB, 512, 0, stream>>>(h, g_s, w2rt, hb, offs, dst_s, agg);
        k_gru<<<(V_N + GNB - 1) / GNB, 512, 0, stream>>>(agg, b_conv, w_ih, w_hh, b_ih, b_hh, b_e2, h, hb);
    }
    k_decoder<<<V_N, 64, 0, stream>>>(h, w_d1, b_d1, w_d2, b_d2, (float*)d_out);
}